// Round 15
// baseline (116.455 us; speedup 1.0000x reference)
//
#include <hip/hip_runtime.h>
#include <hip/hip_bf16.h>

// Problem constants (from reference): B=32, T=256, D=128, tau=0.02
#define B_SZ 32
#define T_SZ 256
#define D_SZ 128
#define TAU_INV 50.0f

typedef __bf16 bf16x8 __attribute__((ext_vector_type(8)));
typedef float f32x4 __attribute__((ext_vector_type(4)));

// masks arrive either as int32 (harness "integer -> int*") or raw bool bytes.
// Element [0][0] is always true (q_len,p_len >= 64), so int32 layout reads 1,
// byte layout reads 0x01010101. Deterministic (input-only) detection.
__device__ __forceinline__ bool mask_is_byte(const void* m) {
    return ((const int*)m)[0] != 1;
}
__device__ __forceinline__ int mget(const void* m, int idx, bool isb) {
    return isb ? (((const unsigned char*)m)[idx] != 0) : (((const int*)m)[idx] != 0);
}

// 8 fp32 -> bf16x8 (compiler emits v_cvt_pk_bf16_f32 pairs; m240: don't hand-asm)
__device__ __forceinline__ bf16x8 cvt8(float4 a, float4 b) {
    union { bf16x8 v; __hip_bfloat16 h[8]; } u;
    u.h[0] = __float2bfloat16(a.x); u.h[1] = __float2bfloat16(a.y);
    u.h[2] = __float2bfloat16(a.z); u.h[3] = __float2bfloat16(a.w);
    u.h[4] = __float2bfloat16(b.x); u.h[5] = __float2bfloat16(b.y);
    u.h[6] = __float2bfloat16(b.z); u.h[7] = __float2bfloat16(b.w);
    return u.v;
}

// ================= ONE kernel: inline cvt + late-interaction + loss =========
// 256 blocks x 1024 threads (1 block/CU, 128 KB LDS). Block (bg, cp): b0=bg,
// b1=bg+16, c0=2cp, c1=2cp+1 (XCD mapping keeps fp32 re-reads L2-local).
// Waves 0-7 own b0 (32 q-rows each), 8-15 own b1. P tiles converted inline
// fp32->bf16 into double-buffered swizzled LDS; c1 loads issued before c0's
// MFMA phase and written after (T14). Last block (fenced counter) computes
// dense sim + all losses and writes out directly.
__global__ __launch_bounds__(1024, 4) void uber(
    const float* __restrict__ qs,  const float* __restrict__ ps,
    const float* __restrict__ qm3, const float* __restrict__ pm3,
    const void* __restrict__ qmask, const void* __restrict__ pmask,
    float* __restrict__ sraw, unsigned int* __restrict__ counter,
    float* __restrict__ out)
{
    __shared__ __align__(16) unsigned char Pl[2][T_SZ * D_SZ * 2]; // 2 x 64 KB
    __shared__ float maddL[2][T_SZ];
    __shared__ float qmulL[2][T_SZ];
    __shared__ float wsum[16][2];
    __shared__ int lastflag;

    const int tid = threadIdx.x;
    const int l   = tid & 63;
    const int w   = tid >> 6;            // wave 0..15
    const int bid = blockIdx.x;
    const int xcd = bid & 7;
    const int j   = bid >> 3;            // 0..31
    const int bg  = xcd * 2 + (j >> 4);  // XCD-local bg
    const int cp  = j & 15;
    const int c0  = cp * 2, c1 = cp * 2 + 1;
    const int b0  = bg, b1 = bg + 16;
    const int lr  = l & 15;
    const int lg  = l >> 4;
    const int wb  = w >> 3;              // 0: b0 waves, 1: b1 waves
    const int myb = wb ? b1 : b0;
    const int s   = (w & 7) * 32;        // this wave's q-row strip

    const bool isb = mask_is_byte(qmask);

    // p-tile compute limits (wave-local reduce over pmask)
    int pt0, pt1;
    {
        int v0 = 0, v1 = 0;
        #pragma unroll
        for (int j2 = 0; j2 < 4; ++j2) {
            int t = l * 4 + j2;
            if (mget(pmask, c0 * T_SZ + t, isb)) v0 = t + 1;
            if (mget(pmask, c1 * T_SZ + t, isb)) v1 = t + 1;
        }
        #pragma unroll
        for (int off = 1; off < 64; off <<= 1) {
            int o0 = __shfl_xor(v0, off), o1 = __shfl_xor(v1, off);
            v0 = o0 > v0 ? o0 : v0;
            v1 = o1 > v1 ? o1 : v1;
        }
        pt0 = ((v0 > 1 ? v0 : 1) + 15) >> 4;
        pt1 = ((v1 > 1 ? v1 : 1) + 15) >> 4;
    }

    // wave-uniform q activity for this wave's 32 rows
    const bool dob = __any(mget(qmask, myb * T_SZ + s + (l & 31), isb));

    // Q fragments inline fp32->bf16: lane holds Q[s+qt*16+lr][k*32+lg*8..]
    bf16x8 qf[2][4] = {};
    if (dob)
        #pragma unroll
        for (int qt = 0; qt < 2; ++qt)
            #pragma unroll
            for (int k = 0; k < 4; ++k) {
                const float4* sp = (const float4*)(qm3 + myb * (T_SZ * D_SZ)
                                    + (s + qt * 16 + lr) * D_SZ + k * 32 + lg * 8);
                qf[qt][k] = cvt8(sp[0], sp[1]);
            }

    // stage c0: fp32 loads + cvt + chunk-swizzled ds_write (cs ^= row&7)
    {
        const float4* Pc = (const float4*)(pm3 + c0 * (T_SZ * D_SZ));
        #pragma unroll
        for (int it = 0; it < 4; ++it) {
            int m = it * 1024 + tid;         // 16B-bf16 chunk id
            int row = m >> 4, cs = m & 15;
            float4 a = Pc[m * 2], b = Pc[m * 2 + 1];
            *(bf16x8*)(Pl[0] + row * 256 + ((cs ^ (row & 7)) << 4)) = cvt8(a, b);
        }
    }
    // mask vectors (per-block, from raw masks)
    {
        int grp = tid >> 8, t = tid & 255;
        if (grp == 0)      maddL[0][t] = mget(pmask, c0 * T_SZ + t, isb) ? 0.0f : -1e30f;
        else if (grp == 1) maddL[1][t] = mget(pmask, c1 * T_SZ + t, isb) ? 0.0f : -1e30f;
        else if (grp == 2) qmulL[0][t] = mget(qmask, b0 * T_SZ + t, isb) ? 1.0f : 0.0f;
        else               qmulL[1][t] = mget(qmask, b1 * T_SZ + t, isb) ? 1.0f : 0.0f;
    }
    __syncthreads();                         // c0 + masks ready

    // issue c1 loads NOW (latency hides under c0 compute; static names, rule #20)
    const float4* Pc1 = (const float4*)(pm3 + c1 * (T_SZ * D_SZ));
    float4 e0 = Pc1[tid * 2],              f0 = Pc1[tid * 2 + 1];
    float4 e1 = Pc1[(1024 + tid) * 2],     f1 = Pc1[(1024 + tid) * 2 + 1];
    float4 e2 = Pc1[(2048 + tid) * 2],     f2 = Pc1[(2048 + tid) * 2 + 1];
    float4 e3 = Pc1[(3072 + tid) * 2],     f3 = Pc1[(3072 + tid) * 2 + 1];

    float r00 = -3e38f, r01 = -3e38f;        // c0: qt0, qt1
    float r10 = -3e38f, r11 = -3e38f;        // c1: qt0, qt1

    for (int pt = 0; pt < pt0; ++pt) {       // ---- compute c0 ----
        f32x4 a0 = {0,0,0,0}, a1 = {0,0,0,0};
        #pragma unroll
        for (int k = 0; k < 4; ++k) {
            int row = pt * 16 + lr;
            bf16x8 af = *(const bf16x8*)(Pl[0] + row * 256 + (((k * 4 + lg) ^ (row & 7)) << 4));
            if (dob) {
                a0 = __builtin_amdgcn_mfma_f32_16x16x32_bf16(af, qf[0][k], a0, 0, 0, 0);
                a1 = __builtin_amdgcn_mfma_f32_16x16x32_bf16(af, qf[1][k], a1, 0, 0, 0);
            }
        }
        float pm0 = maddL[0][pt * 16 + lg * 4 + 0];
        float pm1 = maddL[0][pt * 16 + lg * 4 + 1];
        float pm2 = maddL[0][pt * 16 + lg * 4 + 2];
        float pm3v = maddL[0][pt * 16 + lg * 4 + 3];
        if (dob) {
            r00 = fmaxf(r00, fmaxf(fmaxf(a0[0]+pm0, a0[1]+pm1), fmaxf(a0[2]+pm2, a0[3]+pm3v)));
            r01 = fmaxf(r01, fmaxf(fmaxf(a1[0]+pm0, a1[1]+pm1), fmaxf(a1[2]+pm2, a1[3]+pm3v)));
        }
    }

    // write c1 (loads have landed under c0 compute)
    {
        int m0 = tid, m1 = 1024 + tid, m2 = 2048 + tid, m3 = 3072 + tid;
        *(bf16x8*)(Pl[1] + (m0 >> 4) * 256 + (((m0 & 15) ^ ((m0 >> 4) & 7)) << 4)) = cvt8(e0, f0);
        *(bf16x8*)(Pl[1] + (m1 >> 4) * 256 + (((m1 & 15) ^ ((m1 >> 4) & 7)) << 4)) = cvt8(e1, f1);
        *(bf16x8*)(Pl[1] + (m2 >> 4) * 256 + (((m2 & 15) ^ ((m2 >> 4) & 7)) << 4)) = cvt8(e2, f2);
        *(bf16x8*)(Pl[1] + (m3 >> 4) * 256 + (((m3 & 15) ^ ((m3 >> 4) & 7)) << 4)) = cvt8(e3, f3);
    }
    __syncthreads();                         // c1 staged

    for (int pt = 0; pt < pt1; ++pt) {       // ---- compute c1 ----
        f32x4 a0 = {0,0,0,0}, a1 = {0,0,0,0};
        #pragma unroll
        for (int k = 0; k < 4; ++k) {
            int row = pt * 16 + lr;
            bf16x8 af = *(const bf16x8*)(Pl[1] + row * 256 + (((k * 4 + lg) ^ (row & 7)) << 4));
            if (dob) {
                a0 = __builtin_amdgcn_mfma_f32_16x16x32_bf16(af, qf[0][k], a0, 0, 0, 0);
                a1 = __builtin_amdgcn_mfma_f32_16x16x32_bf16(af, qf[1][k], a1, 0, 0, 0);
            }
        }
        float pm0 = maddL[1][pt * 16 + lg * 4 + 0];
        float pm1 = maddL[1][pt * 16 + lg * 4 + 1];
        float pm2 = maddL[1][pt * 16 + lg * 4 + 2];
        float pm3v = maddL[1][pt * 16 + lg * 4 + 3];
        if (dob) {
            r10 = fmaxf(r10, fmaxf(fmaxf(a0[0]+pm0, a0[1]+pm1), fmaxf(a0[2]+pm2, a0[3]+pm3v)));
            r11 = fmaxf(r11, fmaxf(fmaxf(a1[0]+pm0, a1[1]+pm1), fmaxf(a1[2]+pm2, a1[3]+pm3v)));
        }
    }

    // combine the 4 row-groups (lanes x, 16+x, 32+x, 48+x)
    r00 = fmaxf(r00, __shfl_xor(r00, 16)); r00 = fmaxf(r00, __shfl_xor(r00, 32));
    r01 = fmaxf(r01, __shfl_xor(r01, 16)); r01 = fmaxf(r01, __shfl_xor(r01, 32));
    r10 = fmaxf(r10, __shfl_xor(r10, 16)); r10 = fmaxf(r10, __shfl_xor(r10, 32));
    r11 = fmaxf(r11, __shfl_xor(r11, 16)); r11 = fmaxf(r11, __shfl_xor(r11, 32));

    // masked sum over this wave's 32 q tokens (each value replicated 4x)
    float t0 = r00 * qmulL[wb][s + lr] + r01 * qmulL[wb][s + 16 + lr];   // c0
    float t1 = r10 * qmulL[wb][s + lr] + r11 * qmulL[wb][s + 16 + lr];   // c1
    #pragma unroll
    for (int off = 32; off > 0; off >>= 1) {
        t0 += __shfl_down(t0, off);
        t1 += __shfl_down(t1, off);
    }
    if (l == 0) { wsum[w][0] = t0 * 0.25f; wsum[w][1] = t1 * 0.25f; }
    __syncthreads();

    if (tid < 4) {                           // tid: bit0=c, bit1=b
        const int bsel = tid >> 1, csel = tid & 1;
        float sum = 0.f;
        #pragma unroll
        for (int ww = 0; ww < 8; ++ww) sum += wsum[bsel * 8 + ww][csel];
        sraw[(bsel ? b1 : b0) * 32 + (csel ? c1 : c0)] = sum;
    }
    __threadfence();                         // release sraw stores (all threads)
    __syncthreads();
    if (tid == 0) {
        unsigned int old = atomicAdd(counter, 1u);
        lastflag = (old == (unsigned int)(gridDim.x - 1));
    }
    __syncthreads();
    if (!lastflag) return;

    // ================== last block: dense sim + losses ======================
    __threadfence();                         // acquire all sraw stores

    float* base   = (float*)Pl;              // LDS reuse
    float* denseA = base;                    // [1024]
    float* lateA  = base + 1024;             // [1024]
    float* tcntL  = base + 2048;             // [32]
    float* rsA    = base + 2080;             // [32]
    float* rmA    = rsA + 32;
    float* rkA    = rmA + 32;

    // tcnt: wave w, half h=(l>=32): row = w*2+h, 32 lanes x 8 tokens
    {
        const int h = l >> 5, lane32 = l & 31;
        const int r = w * 2 + h;
        int cnt = 0;
        #pragma unroll
        for (int k = 0; k < 8; ++k)
            cnt += mget(qmask, r * T_SZ + lane32 + k * 32, isb);
        #pragma unroll
        for (int off = 1; off < 32; off <<= 1) cnt += __shfl_xor(cnt, off);
        if (lane32 == 0) tcntL[r] = (float)(cnt > 1 ? cnt : 1);
    }
    __syncthreads();

    // dense + late: 1 thread per (r, cc) pair, full 128-elem dot
    {
        const int r = tid >> 5, cc = tid & 31;
        const float4* qa = (const float4*)(qs + r  * D_SZ);
        const float4* pb = (const float4*)(ps + cc * D_SZ);
        float sdot = 0.f;
        #pragma unroll
        for (int i = 0; i < 32; ++i) {
            float4 a = qa[i], b = pb[i];
            sdot += a.x * b.x + a.y * b.y + a.z * b.z + a.w * b.w;
        }
        denseA[tid] = sdot;
        lateA[tid]  = sraw[tid] / tcntL[r];
    }
    __syncthreads();

    // softmax/CE/KL: wave w, half h -> row = w*2+h (32 lanes per row)
    {
        const int h = l >> 5, lane32 = l & 31;
        const int r = w * 2 + h;
        float xd = denseA[r * 32 + lane32] * TAU_INV;
        float xl = lateA[r * 32 + lane32]  * TAU_INV;
        float md = xd, ml = xl;
        #pragma unroll
        for (int off = 16; off > 0; off >>= 1) {
            md = fmaxf(md, __shfl_xor(md, off));
            ml = fmaxf(ml, __shfl_xor(ml, off));
        }
        float sd = expf(xd - md), sl = expf(xl - ml);
        #pragma unroll
        for (int off = 16; off > 0; off >>= 1) {
            sd += __shfl_xor(sd, off);
            sl += __shfl_xor(sl, off);
        }
        float lsd = md + logf(sd);
        float lsl = ml + logf(sl);
        float pd = expf(xd - lsd);
        float pl = expf(xl - lsl);
        float klt = pd * logf((pd + 1e-8f) / (pl + 1e-8f));
        #pragma unroll
        for (int off = 16; off > 0; off >>= 1) klt += __shfl_xor(klt, off);

        float logpd = xd - lsd;              // lane lane32 holds col lane32
        float logpl = xl - lsl;
        int srcLane = (l & 32) + r;          // diagonal lane within this half
        float dlogd = __shfl(logpd, srcLane);
        float dlogl = __shfl(logpl, srcLane);
        if (lane32 == 0) {
            rsA[r] = -dlogd;
            rmA[r] = -dlogl;
            rkA[r] = klt;
        }
    }
    __syncthreads();

    if (tid < 32) {
        float a = rsA[tid], bb = rmA[tid], c2 = rkA[tid];
        #pragma unroll
        for (int off = 16; off > 0; off >>= 1) {
            a  += __shfl_xor(a, off);
            bb += __shfl_xor(bb, off);
            c2 += __shfl_xor(c2, off);
        }
        if (tid == 0) {
            a *= (1.0f / B_SZ); bb *= (1.0f / B_SZ); c2 *= (1.0f / B_SZ);
            out[0] = a + bb + c2;  // total
            out[1] = a;            // single_loss
            out[2] = bb;           // multi_loss
            out[3] = c2;           // kl
        }
    }
}

// ---------------------------------------------------------------------------
extern "C" void kernel_launch(void* const* d_in, const int* in_sizes, int n_in,
                              void* d_out, int out_size, void* d_ws, size_t ws_size,
                              hipStream_t stream) {
    const float* qs    = (const float*)d_in[0];  // query_single [32,128]
    const float* ps    = (const float*)d_in[1];  // pos_single   [32,128]
    const float* qm3   = (const float*)d_in[2];  // query_multi  [32,256,128]
    const float* pm3   = (const float*)d_in[3];  // pos_multi    [32,256,128]
    const void*  qmask = d_in[4];                // q_mask [32,256]
    const void*  pmask = d_in[5];                // p_mask [32,256]
    float* out = (float*)d_out;

    float* sraw = (float*)d_ws;                               // [1024]
    unsigned int* counter = (unsigned int*)((char*)d_ws + 4096);

    hipMemsetAsync(counter, 0, sizeof(unsigned int), stream); // graph-capturable
    uber<<<256, 1024, 0, stream>>>(qs, ps, qm3, pm3, qmask, pmask,
                                   sraw, counter, out);
}

// Round 16
// 61.357 us; speedup vs baseline: 1.8980x; 1.8980x over previous
//
#include <hip/hip_runtime.h>
#include <hip/hip_bf16.h>

// Problem constants (from reference): B=32, T=256, D=128, tau=0.02
#define B_SZ 32
#define T_SZ 256
#define D_SZ 128
#define TAU_INV 50.0f

typedef __bf16 bf16x8 __attribute__((ext_vector_type(8)));
typedef float f32x4 __attribute__((ext_vector_type(4)));

__device__ __forceinline__ unsigned short f2bf(float f) {
    union { float f; unsigned int u; } v; v.f = f;
    unsigned int r = v.u + 0x7fffu + ((v.u >> 16) & 1u);  // RNE
    return (unsigned short)(r >> 16);
}

// masks arrive either as int32 (harness "integer -> int*") or raw bool bytes.
// Element [0][0] is always true (q_len,p_len >= 64), so int32 layout reads 1,
// byte layout reads 0x01010101. Deterministic (input-only) detection.
__device__ __forceinline__ bool mask_is_byte(const void* m) {
    return ((const int*)m)[0] != 1;
}
__device__ __forceinline__ int mget(const void* m, int idx, bool isb) {
    return isb ? (((const unsigned char*)m)[idx] != 0) : (((const int*)m)[idx] != 0);
}

// ---------------- Kernel A: fp32->bf16 + mask tables (R14, unchanged) -------
__global__ __launch_bounds__(256) void cvt_prep2(
    const float* __restrict__ qsrc, const float* __restrict__ psrc,
    const void* __restrict__ qmask, const void* __restrict__ pmask,
    unsigned short* __restrict__ Qb, unsigned short* __restrict__ Pb,
    float* __restrict__ maddF, float* __restrict__ qmulF,
    int* __restrict__ p_hiA, float* __restrict__ tcntA) {
    const int tid = threadIdx.x;
    if (blockIdx.x < 512) {
        int i = (blockIdx.x * 256 + tid) * 8;
        const float4* q4 = (const float4*)(qsrc + i);
        const float4* p4 = (const float4*)(psrc + i);
        float4 a0 = q4[0], a1 = q4[1], b0 = p4[0], b1 = p4[1];
        ushort4 oq0 = { f2bf(a0.x), f2bf(a0.y), f2bf(a0.z), f2bf(a0.w) };
        ushort4 oq1 = { f2bf(a1.x), f2bf(a1.y), f2bf(a1.z), f2bf(a1.w) };
        ushort4 op0 = { f2bf(b0.x), f2bf(b0.y), f2bf(b0.z), f2bf(b0.w) };
        ushort4 op1 = { f2bf(b1.x), f2bf(b1.y), f2bf(b1.z), f2bf(b1.w) };
        *(ushort4*)(Qb + i)     = oq0;
        *(ushort4*)(Qb + i + 4) = oq1;
        *(ushort4*)(Pb + i)     = op0;
        *(ushort4*)(Pb + i + 4) = op1;
        return;
    }
    __shared__ int sl[4], sc[4];
    const bool isb = mask_is_byte(qmask);
    const int r = blockIdx.x - 512;              // 0..31
    const int t = tid;                           // 0..255 (= T_SZ)
    const int pm = mget(pmask, r * T_SZ + t, isb);
    const int qm = mget(qmask, r * T_SZ + t, isb);
    maddF[r * T_SZ + t] = pm ? 0.0f : -1e30f;
    qmulF[r * T_SZ + t] = qm ? 1.0f : 0.0f;
    int lp = pm ? t + 1 : 0, cq = qm;
    #pragma unroll
    for (int off = 1; off < 64; off <<= 1) {
        int o = __shfl_xor(lp, off);
        lp = o > lp ? o : lp;
        cq += __shfl_xor(cq, off);
    }
    if ((tid & 63) == 0) { sl[tid >> 6] = lp; sc[tid >> 6] = cq; }
    __syncthreads();
    if (tid == 0) {
        int LP = sl[0], CQ = sc[0];
        #pragma unroll
        for (int i = 1; i < 4; ++i) { LP = sl[i] > LP ? sl[i] : LP; CQ += sc[i]; }
        p_hiA[r] = LP > 1 ? LP : 1;
        tcntA[r] = (float)(CQ > 1 ? CQ : 1);
    }
}

// ---------------- Kernel B: late-interaction (R14 core), 3x REPLICATED ------
// MEASUREMENT ROUND: grid = 3 x 256. Replica 0 writes sraw; replicas 1,2
// compute identically but write srawD (dummy ws region) -> kernel duration
// ~3x the real cost, pushing it above the 40-us poison fills into the rocprof
// top-5 WITH counters. Output identical & deterministic.
__global__ __launch_bounds__(1024, 4) void late_sim2(
    const unsigned short* __restrict__ Qbf, const unsigned short* __restrict__ Pbf,
    const float* __restrict__ maddF, const float* __restrict__ qmulF,
    const int* __restrict__ p_hiA, float* __restrict__ sraw,
    float* __restrict__ srawD)
{
    __shared__ __align__(16) unsigned char Pl[2][T_SZ * D_SZ * 2]; // 2 x 64 KB
    __shared__ float maddL[2][T_SZ];
    __shared__ float qmulL[2][T_SZ];
    __shared__ float wsum[16][2];

    const int tid = threadIdx.x;
    const int l   = tid & 63;
    const int w   = tid >> 6;            // wave 0..15
    const int rep = blockIdx.x >> 8;     // 0..2 (replica)
    const int bid = blockIdx.x & 255;
    float* sout = (rep == 0) ? sraw : (srawD + (rep - 1) * 1024);
    const int xcd = bid & 7;
    const int j   = bid >> 3;            // 0..31
    const int bg  = xcd * 2 + (j >> 4);  // XCD-local bg
    const int cp  = j & 15;
    const int c0  = cp * 2, c1 = cp * 2 + 1;
    const int b0  = bg, b1 = bg + 16;
    const int lr  = l & 15;
    const int lg  = l >> 4;
    const int wb  = w >> 3;              // 0: b0 waves, 1: b1 waves
    const int myb = wb ? b1 : b0;
    const int s   = (w & 7) * 32;        // this wave's q-row strip

    const int p_hi0 = p_hiA[c0], p_hi1 = p_hiA[c1];
    const int pt0 = (p_hi0 + 15) >> 4, st0 = (p_hi0 + 63) >> 6;
    const int pt1 = (p_hi1 + 15) >> 4, st1 = (p_hi1 + 63) >> 6;

    const bool dob = __any(qmulF[myb * T_SZ + s + (l & 31)] > 0.0f);

    // Q fragments (one b per wave)
    bf16x8 qf[2][4] = {};
    if (dob)
        #pragma unroll
        for (int qt = 0; qt < 2; ++qt)
            #pragma unroll
            for (int k = 0; k < 4; ++k)
                qf[qt][k] = *(const bf16x8*)(Qbf + myb * (T_SZ * D_SZ)
                              + (s + qt * 16 + lr) * D_SZ + k * 32 + lg * 8);

    // stage c0 (buffer 0)
    {
        const unsigned short* Pc = Pbf + c0 * (T_SZ * D_SZ);
        for (int it = 0; it < st0; ++it) {
            int m   = it * 1024 + tid;
            int row = m >> 4;
            int cj  = m & 15;
            const unsigned short* src = Pc + row * D_SZ + ((cj ^ (row & 7)) << 3);
            __builtin_amdgcn_global_load_lds(
                (const __attribute__((address_space(1))) unsigned int*)src,
                (__attribute__((address_space(3))) unsigned int*)(Pl[0] + (it * 1024 + w * 64) * 16),
                16, 0, 0);
        }
    }
    if (tid < 64) {
        *(float4*)(maddL[0] + tid * 4) = *(const float4*)(maddF + c0 * T_SZ + tid * 4);
    } else if (tid < 128) {
        int t = tid - 64;
        *(float4*)(maddL[1] + t * 4) = *(const float4*)(maddF + c1 * T_SZ + t * 4);
    } else if (tid < 192) {
        int t = tid - 128;
        *(float4*)(qmulL[0] + t * 4) = *(const float4*)(qmulF + b0 * T_SZ + t * 4);
    } else if (tid < 256) {
        int t = tid - 192;
        *(float4*)(qmulL[1] + t * 4) = *(const float4*)(qmulF + b1 * T_SZ + t * 4);
    }
    __syncthreads();

    // issue c1 staging (hides under c0 compute)
    {
        const unsigned short* Pc = Pbf + c1 * (T_SZ * D_SZ);
        for (int it = 0; it < st1; ++it) {
            int m   = it * 1024 + tid;
            int row = m >> 4;
            int cj  = m & 15;
            const unsigned short* src = Pc + row * D_SZ + ((cj ^ (row & 7)) << 3);
            __builtin_amdgcn_global_load_lds(
                (const __attribute__((address_space(1))) unsigned int*)src,
                (__attribute__((address_space(3))) unsigned int*)(Pl[1] + (it * 1024 + w * 64) * 16),
                16, 0, 0);
        }
    }

    float r00 = -3e38f, r01 = -3e38f;
    float r10 = -3e38f, r11 = -3e38f;

    for (int pt = 0; pt < pt0; ++pt) {           // ---- compute c0 ----
        f32x4 a0 = {0,0,0,0}, a1 = {0,0,0,0};
        #pragma unroll
        for (int k = 0; k < 4; ++k) {
            int row = pt * 16 + lr;
            bf16x8 af = *(const bf16x8*)(Pl[0] + row * 256 + (((k * 4 + lg) ^ (row & 7)) << 4));
            if (dob) {
                a0 = __builtin_amdgcn_mfma_f32_16x16x32_bf16(af, qf[0][k], a0, 0, 0, 0);
                a1 = __builtin_amdgcn_mfma_f32_16x16x32_bf16(af, qf[1][k], a1, 0, 0, 0);
            }
        }
        float pm0 = maddL[0][pt * 16 + lg * 4 + 0];
        float pm1 = maddL[0][pt * 16 + lg * 4 + 1];
        float pm2 = maddL[0][pt * 16 + lg * 4 + 2];
        float pm3 = maddL[0][pt * 16 + lg * 4 + 3];
        if (dob) {
            r00 = fmaxf(r00, fmaxf(fmaxf(a0[0]+pm0, a0[1]+pm1), fmaxf(a0[2]+pm2, a0[3]+pm3)));
            r01 = fmaxf(r01, fmaxf(fmaxf(a1[0]+pm0, a1[1]+pm1), fmaxf(a1[2]+pm2, a1[3]+pm3)));
        }
    }
    __syncthreads();                             // c1 staged (vmcnt drained)

    for (int pt = 0; pt < pt1; ++pt) {           // ---- compute c1 ----
        f32x4 a0 = {0,0,0,0}, a1 = {0,0,0,0};
        #pragma unroll
        for (int k = 0; k < 4; ++k) {
            int row = pt * 16 + lr;
            bf16x8 af = *(const bf16x8*)(Pl[1] + row * 256 + (((k * 4 + lg) ^ (row & 7)) << 4));
            if (dob) {
                a0 = __builtin_amdgcn_mfma_f32_16x16x32_bf16(af, qf[0][k], a0, 0, 0, 0);
                a1 = __builtin_amdgcn_mfma_f32_16x16x32_bf16(af, qf[1][k], a1, 0, 0, 0);
            }
        }
        float pm0 = maddL[1][pt * 16 + lg * 4 + 0];
        float pm1 = maddL[1][pt * 16 + lg * 4 + 1];
        float pm2 = maddL[1][pt * 16 + lg * 4 + 2];
        float pm3 = maddL[1][pt * 16 + lg * 4 + 3];
        if (dob) {
            r10 = fmaxf(r10, fmaxf(fmaxf(a0[0]+pm0, a0[1]+pm1), fmaxf(a0[2]+pm2, a0[3]+pm3)));
            r11 = fmaxf(r11, fmaxf(fmaxf(a1[0]+pm0, a1[1]+pm1), fmaxf(a1[2]+pm2, a1[3]+pm3)));
        }
    }

    r00 = fmaxf(r00, __shfl_xor(r00, 16)); r00 = fmaxf(r00, __shfl_xor(r00, 32));
    r01 = fmaxf(r01, __shfl_xor(r01, 16)); r01 = fmaxf(r01, __shfl_xor(r01, 32));
    r10 = fmaxf(r10, __shfl_xor(r10, 16)); r10 = fmaxf(r10, __shfl_xor(r10, 32));
    r11 = fmaxf(r11, __shfl_xor(r11, 16)); r11 = fmaxf(r11, __shfl_xor(r11, 32));

    float t0 = r00 * qmulL[wb][s + lr] + r01 * qmulL[wb][s + 16 + lr];   // c0
    float t1 = r10 * qmulL[wb][s + lr] + r11 * qmulL[wb][s + 16 + lr];   // c1
    #pragma unroll
    for (int off = 32; off > 0; off >>= 1) {
        t0 += __shfl_down(t0, off);
        t1 += __shfl_down(t1, off);
    }
    if (l == 0) { wsum[w][0] = t0 * 0.25f; wsum[w][1] = t1 * 0.25f; }
    __syncthreads();

    if (tid < 4) {
        const int bsel = tid >> 1, csel = tid & 1;
        float sum = 0.f;
        #pragma unroll
        for (int ww = 0; ww < 8; ++ww) sum += wsum[bsel * 8 + ww][csel];
        sout[(bsel ? b1 : b0) * 32 + (csel ? c1 : c0)] = sum;
    }
}

// ---------------- Kernel C: losses, one block PER ROW (R14, unchanged) ------
__global__ __launch_bounds__(256) void loss_row(
    const float* __restrict__ qs, const float* __restrict__ ps,
    const float* __restrict__ sraw, const float* __restrict__ tcntA,
    float* __restrict__ out)
{
    __shared__ float denseL[B_SZ], lateL[B_SZ];
    const int r   = blockIdx.x;
    const int tid = threadIdx.x;
    const int cc  = tid >> 3;
    const int j   = tid & 7;

    {
        const float4* qa = (const float4*)(qs + r  * D_SZ + j * 16);
        const float4* pb = (const float4*)(ps + cc * D_SZ + j * 16);
        float s = 0.f;
        #pragma unroll
        for (int v = 0; v < 4; ++v) {
            float4 q = qa[v], p = pb[v];
            s += q.x * p.x + q.y * p.y + q.z * p.z + q.w * p.w;
        }
        s += __shfl_xor(s, 1);
        s += __shfl_xor(s, 2);
        s += __shfl_xor(s, 4);
        if (j == 0) denseL[cc] = s;
    }
    if (tid < B_SZ) lateL[tid] = sraw[r * 32 + tid] / tcntA[r];
    __syncthreads();

    if (tid >= 32) return;
    const int lane = tid;
    float xd = denseL[lane] * TAU_INV;
    float xl = lateL[lane]  * TAU_INV;
    float md = xd, ml = xl;
    #pragma unroll
    for (int off = 16; off > 0; off >>= 1) {
        md = fmaxf(md, __shfl_xor(md, off));
        ml = fmaxf(ml, __shfl_xor(ml, off));
    }
    float sd = expf(xd - md), sl = expf(xl - ml);
    #pragma unroll
    for (int off = 16; off > 0; off >>= 1) {
        sd += __shfl_xor(sd, off);
        sl += __shfl_xor(sl, off);
    }
    float lsd = md + logf(sd);
    float lsl = ml + logf(sl);
    float pd = expf(xd - lsd);
    float pl = expf(xl - lsl);
    float klt = pd * logf((pd + 1e-8f) / (pl + 1e-8f));
    #pragma unroll
    for (int off = 16; off > 0; off >>= 1) klt += __shfl_xor(klt, off);

    float logpd = xd - lsd;
    float logpl = xl - lsl;
    float dlogd = __shfl(logpd, r);
    float dlogl = __shfl(logpl, r);

    if (lane == 0) {
        const float inv = 1.0f / (float)B_SZ;
        float a = -dlogd * inv;
        float b = -dlogl * inv;
        float k = klt * inv;
        atomicAdd(out + 1, a);
        atomicAdd(out + 2, b);
        atomicAdd(out + 3, k);
        atomicAdd(out + 0, a + b + k);
    }
}

// ---------------------------------------------------------------------------
extern "C" void kernel_launch(void* const* d_in, const int* in_sizes, int n_in,
                              void* d_out, int out_size, void* d_ws, size_t ws_size,
                              hipStream_t stream) {
    const float* qs    = (const float*)d_in[0];  // query_single [32,128]
    const float* ps    = (const float*)d_in[1];  // pos_single   [32,128]
    const float* qm3   = (const float*)d_in[2];  // query_multi  [32,256,128]
    const float* pm3   = (const float*)d_in[3];  // pos_multi    [32,256,128]
    const void*  qmask = d_in[4];                // q_mask [32,256]
    const void*  pmask = d_in[5];                // p_mask [32,256]
    float* out = (float*)d_out;

    const int NTOK = B_SZ * T_SZ * D_SZ;         // 1,048,576
    unsigned short* Qbf = (unsigned short*)d_ws;
    unsigned short* Pbf = Qbf + NTOK;
    float* sraw  = (float*)(Pbf + NTOK);         // [1024]
    float* maddF = sraw + 1024;                  // [32*256]
    float* qmulF = maddF + B_SZ * T_SZ;          // [32*256]
    int*   p_hiA = (int*)(qmulF + B_SZ * T_SZ);  // [32]
    float* tcntA = (float*)(p_hiA + 32);         // [32]
    float* srawD = tcntA + 32;                   // [2048] dummy for replicas

    hipMemsetAsync(out, 0, 4 * sizeof(float), stream);  // atomics accumulate
    cvt_prep2<<<544, 256, 0, stream>>>(qm3, pm3, qmask, pmask, Qbf, Pbf,
                                       maddF, qmulF, p_hiA, tcntA);
    late_sim2<<<3 * 256, 1024, 0, stream>>>(Qbf, Pbf, maddF, qmulF, p_hiA,
                                            sraw, srawD);
    loss_row<<<B_SZ, 256, 0, stream>>>(qs, ps, sraw, tcntA, out);
}

// Round 17
// 36.122 us; speedup vs baseline: 3.2239x; 1.6986x over previous
//
#include <hip/hip_runtime.h>
#include <hip/hip_bf16.h>

// Problem constants (from reference): B=32, T=256, D=128, tau=0.02
#define B_SZ 32
#define T_SZ 256
#define D_SZ 128
#define TAU_INV 50.0f

typedef __bf16 bf16x8 __attribute__((ext_vector_type(8)));
typedef float f32x4 __attribute__((ext_vector_type(4)));

__device__ __forceinline__ unsigned short f2bf(float f) {
    union { float f; unsigned int u; } v; v.f = f;
    unsigned int r = v.u + 0x7fffu + ((v.u >> 16) & 1u);  // RNE
    return (unsigned short)(r >> 16);
}

// masks arrive either as int32 (harness "integer -> int*") or raw bool bytes.
// Element [0][0] is always true (q_len,p_len >= 64), so int32 layout reads 1,
// byte layout reads 0x01010101. Deterministic (input-only) detection.
__device__ __forceinline__ bool mask_is_byte(const void* m) {
    return ((const int*)m)[0] != 1;
}
__device__ __forceinline__ int mget(const void* m, int idx, bool isb) {
    return isb ? (((const unsigned char*)m)[idx] != 0) : (((const int*)m)[idx] != 0);
}

// ---------------- Kernel A: pure fp32->bf16 (512 blocks) --------------------
__global__ __launch_bounds__(256) void cvt2(
    const float* __restrict__ qsrc, const float* __restrict__ psrc,
    unsigned short* __restrict__ Qb, unsigned short* __restrict__ Pb) {
    const int tid = threadIdx.x;
    int i = (blockIdx.x * 256 + tid) * 8;
    const float4* q4 = (const float4*)(qsrc + i);
    const float4* p4 = (const float4*)(psrc + i);
    float4 a0 = q4[0], a1 = q4[1], b0 = p4[0], b1 = p4[1];
    ushort4 oq0 = { f2bf(a0.x), f2bf(a0.y), f2bf(a0.z), f2bf(a0.w) };
    ushort4 oq1 = { f2bf(a1.x), f2bf(a1.y), f2bf(a1.z), f2bf(a1.w) };
    ushort4 op0 = { f2bf(b0.x), f2bf(b0.y), f2bf(b0.z), f2bf(b0.w) };
    ushort4 op1 = { f2bf(b1.x), f2bf(b1.y), f2bf(b1.z), f2bf(b1.w) };
    *(ushort4*)(Qb + i)     = oq0;
    *(ushort4*)(Qb + i + 4) = oq1;
    *(ushort4*)(Pb + i)     = op0;
    *(ushort4*)(Pb + i + 4) = op1;
}

// ---------------- Kernel B: late-interaction, 4-MFMA-per-LDS-read -----------
// 512 blocks x 512 threads, ~68 KB LDS -> 2 blocks/CU co-resident (one block
// stages while the other computes). Block (bg, c): b0=bg, b1=bg+16 (XCD-local
// bg for L2 locality). 8 waves: waves 0-3 own b0, 4-7 own b1; each wave owns
// 64 q-rows (qf[4][4], 64 VGPR) -> every ds_read_b128 of the P fragment feeds
// 4 MFMAs (vs 2 in R13-16; halves LDS-pipe traffic, the measured binding
// resource: 17.7% MfmaUtil / 10.2us LDS time in R16's replication probe).
// Masks/p_hi computed in-kernel (R7-validated). Work-skip exact.
__global__ __launch_bounds__(512, 4) void late3(
    const unsigned short* __restrict__ Qbf, const unsigned short* __restrict__ Pbf,
    const void* __restrict__ qmask, const void* __restrict__ pmask,
    float* __restrict__ sraw)
{
    __shared__ __align__(16) unsigned char Plds[T_SZ * D_SZ * 2]; // 64 KB
    __shared__ float madd[T_SZ];
    __shared__ float qmul[2][T_SZ];
    __shared__ float wsum[8];

    const int tid = threadIdx.x;
    const int l   = tid & 63;
    const int w   = tid >> 6;            // wave 0..7
    const int bid = blockIdx.x;
    const int xcd = bid & 7;
    const int idx = bid >> 3;            // 0..63
    const int bg  = xcd * 2 + (idx >> 5);
    const int c   = idx & 31;
    const int b0  = bg, b1 = bg + 16;
    const int lr  = l & 15;
    const int lg  = l >> 4;
    const int wb  = w >> 2;              // 0: b0 waves, 1: b1 waves
    const int myb = wb ? b1 : b0;
    const int s   = (w & 3) * 64;        // this wave's 64-row q strip

    const bool isb = mask_is_byte(qmask);

    // p_hi (last valid p index + 1), wave-local reduce
    int p_hi;
    {
        int v = 0;
        #pragma unroll
        for (int j2 = 0; j2 < 4; ++j2) {
            int t = l * 4 + j2;
            if (mget(pmask, c * T_SZ + t, isb)) v = t + 1;
        }
        #pragma unroll
        for (int off = 1; off < 64; off <<= 1) {
            int o = __shfl_xor(v, off);
            v = o > v ? o : v;
        }
        p_hi = v > 1 ? v : 1;
    }
    const int ptmax   = (p_hi + 15) >> 4;
    const int stiters = (p_hi + 31) >> 5;   // 32 rows per staging iter

    // wave-uniform q activity over this wave's 64 rows
    const bool dob = __any(mget(qmask, myb * T_SZ + s + l, isb));

    // Q fragments: lane holds Q[s+qt*16+lr][k*32+lg*8 .. +7]
    bf16x8 qf[4][4] = {};
    if (dob)
        #pragma unroll
        for (int qt = 0; qt < 4; ++qt)
            #pragma unroll
            for (int k = 0; k < 4; ++k)
                qf[qt][k] = *(const bf16x8*)(Qbf + myb * (T_SZ * D_SZ)
                              + (s + qt * 16 + lr) * D_SZ + k * 32 + lg * 8);

    // stage P rows [0, stiters*32): global_load_lds, linear LDS dest,
    // inverse-swizzled global source (read-side XOR -> net identity, rule #21)
    {
        const unsigned short* Pc = Pbf + c * (T_SZ * D_SZ);
        for (int it = 0; it < stiters; ++it) {
            int m   = it * 512 + w * 64 + l;     // linear 16B chunk id
            int row = m >> 4;
            int cj  = m & 15;
            const unsigned short* src = Pc + row * D_SZ + ((cj ^ (row & 7)) << 3);
            __builtin_amdgcn_global_load_lds(
                (const __attribute__((address_space(1))) unsigned int*)src,
                (__attribute__((address_space(3))) unsigned int*)(Plds + (it * 512 + w * 64) * 16),
                16, 0, 0);
        }
    }
    // mask vectors (in-kernel, from raw masks)
    if (tid < 256) {
        madd[tid]    = mget(pmask, c  * T_SZ + tid, isb) ? 0.0f : -1e30f;
        qmul[0][tid] = mget(qmask, b0 * T_SZ + tid, isb) ? 1.0f : 0.0f;
    } else {
        int t = tid - 256;
        qmul[1][t]   = mget(qmask, b1 * T_SZ + t, isb) ? 1.0f : 0.0f;
    }
    __syncthreads();   // staging + qf loads drained

    float r0 = -3e38f, r1 = -3e38f, r2 = -3e38f, r3 = -3e38f;

    for (int pt = 0; pt < ptmax; ++pt) {
        f32x4 a0 = {0,0,0,0}, a1 = {0,0,0,0}, a2 = {0,0,0,0}, a3 = {0,0,0,0};
        #pragma unroll
        for (int k = 0; k < 4; ++k) {
            int row = pt * 16 + lr;
            bf16x8 af = *(const bf16x8*)(Plds + row * 256 + (((k * 4 + lg) ^ (row & 7)) << 4));
            if (dob) {
                a0 = __builtin_amdgcn_mfma_f32_16x16x32_bf16(af, qf[0][k], a0, 0, 0, 0);
                a1 = __builtin_amdgcn_mfma_f32_16x16x32_bf16(af, qf[1][k], a1, 0, 0, 0);
                a2 = __builtin_amdgcn_mfma_f32_16x16x32_bf16(af, qf[2][k], a2, 0, 0, 0);
                a3 = __builtin_amdgcn_mfma_f32_16x16x32_bf16(af, qf[3][k], a3, 0, 0, 0);
            }
        }
        // C layout: col(q)=lane&15, row(p)= pt*16 + lg*4 + reg
        float pm0 = madd[pt * 16 + lg * 4 + 0];
        float pm1 = madd[pt * 16 + lg * 4 + 1];
        float pm2 = madd[pt * 16 + lg * 4 + 2];
        float pm3 = madd[pt * 16 + lg * 4 + 3];
        if (dob) {
            r0 = fmaxf(r0, fmaxf(fmaxf(a0[0]+pm0, a0[1]+pm1), fmaxf(a0[2]+pm2, a0[3]+pm3)));
            r1 = fmaxf(r1, fmaxf(fmaxf(a1[0]+pm0, a1[1]+pm1), fmaxf(a1[2]+pm2, a1[3]+pm3)));
            r2 = fmaxf(r2, fmaxf(fmaxf(a2[0]+pm0, a2[1]+pm1), fmaxf(a2[2]+pm2, a2[3]+pm3)));
            r3 = fmaxf(r3, fmaxf(fmaxf(a3[0]+pm0, a3[1]+pm1), fmaxf(a3[2]+pm2, a3[3]+pm3)));
        }
    }

    // combine the 4 row-groups (lanes x, 16+x, 32+x, 48+x)
    r0 = fmaxf(r0, __shfl_xor(r0, 16)); r0 = fmaxf(r0, __shfl_xor(r0, 32));
    r1 = fmaxf(r1, __shfl_xor(r1, 16)); r1 = fmaxf(r1, __shfl_xor(r1, 32));
    r2 = fmaxf(r2, __shfl_xor(r2, 16)); r2 = fmaxf(r2, __shfl_xor(r2, 32));
    r3 = fmaxf(r3, __shfl_xor(r3, 16)); r3 = fmaxf(r3, __shfl_xor(r3, 32));

    // masked sum over this wave's 64 q tokens (each value replicated 4x)
    float t0 = r0 * qmul[wb][s + lr]      + r1 * qmul[wb][s + 16 + lr]
             + r2 * qmul[wb][s + 32 + lr] + r3 * qmul[wb][s + 48 + lr];
    #pragma unroll
    for (int off = 32; off > 0; off >>= 1) t0 += __shfl_down(t0, off);
    if (l == 0) wsum[w] = t0 * 0.25f;
    __syncthreads();

    if (tid < 2) {
        float sum = wsum[tid * 4] + wsum[tid * 4 + 1]
                  + wsum[tid * 4 + 2] + wsum[tid * 4 + 3];
        sraw[(tid ? b1 : b0) * 32 + c] = sum;
    }
}

// ---------------- Kernel C: losses, one block PER ROW (32 blocks) -----------
// Block r: dense row r (8 thr/col x 16 elems), tcnt in-kernel, 32-lane
// softmax/CE/KL, atomicAdd /32 contribution (out zeroed by memset node).
__global__ __launch_bounds__(256) void loss_row2(
    const float* __restrict__ qs, const float* __restrict__ ps,
    const float* __restrict__ sraw, const void* __restrict__ qmask,
    float* __restrict__ out)
{
    __shared__ float denseL[B_SZ];
    __shared__ float stcnt;
    const int r   = blockIdx.x;
    const int tid = threadIdx.x;
    const int cc  = tid >> 3;
    const int j   = tid & 7;
    const bool isb = mask_is_byte(qmask);

    // dot(qs[r], ps[cc]): 8 threads x 16 elems (4x float4), 3-round reduce
    {
        const float4* qa = (const float4*)(qs + r  * D_SZ + j * 16);
        const float4* pb = (const float4*)(ps + cc * D_SZ + j * 16);
        float s = 0.f;
        #pragma unroll
        for (int v = 0; v < 4; ++v) {
            float4 q = qa[v], p = pb[v];
            s += q.x * p.x + q.y * p.y + q.z * p.z + q.w * p.w;
        }
        s += __shfl_xor(s, 1);
        s += __shfl_xor(s, 2);
        s += __shfl_xor(s, 4);
        if (j == 0) denseL[cc] = s;
    }
    if (tid < 32) {                       // tcnt for row r (32 lanes x 8 tokens)
        int cnt = 0;
        #pragma unroll
        for (int k = 0; k < 8; ++k)
            cnt += mget(qmask, r * T_SZ + tid + k * 32, isb);
        #pragma unroll
        for (int off = 1; off < 32; off <<= 1) cnt += __shfl_xor(cnt, off);
        if (tid == 0) stcnt = (float)(cnt > 1 ? cnt : 1);
    }
    __syncthreads();

    if (tid >= 32) return;
    const int lane = tid;
    float xd = denseL[lane] * TAU_INV;
    float xl = (sraw[r * 32 + lane] / stcnt) * TAU_INV;
    float md = xd, ml = xl;
    #pragma unroll
    for (int off = 16; off > 0; off >>= 1) {
        md = fmaxf(md, __shfl_xor(md, off));
        ml = fmaxf(ml, __shfl_xor(ml, off));
    }
    float sd = expf(xd - md), sl = expf(xl - ml);
    #pragma unroll
    for (int off = 16; off > 0; off >>= 1) {
        sd += __shfl_xor(sd, off);
        sl += __shfl_xor(sl, off);
    }
    float lsd = md + logf(sd);
    float lsl = ml + logf(sl);
    float pd = expf(xd - lsd);
    float pl = expf(xl - lsl);
    float klt = pd * logf((pd + 1e-8f) / (pl + 1e-8f));
    #pragma unroll
    for (int off = 16; off > 0; off >>= 1) klt += __shfl_xor(klt, off);

    float logpd = xd - lsd;
    float logpl = xl - lsl;
    float dlogd = __shfl(logpd, r);       // diagonal entry (lane r)
    float dlogl = __shfl(logpl, r);

    if (lane == 0) {
        const float inv = 1.0f / (float)B_SZ;
        float a = -dlogd * inv;
        float b = -dlogl * inv;
        float k = klt * inv;
        atomicAdd(out + 1, a);
        atomicAdd(out + 2, b);
        atomicAdd(out + 3, k);
        atomicAdd(out + 0, a + b + k);
    }
}

// ---------------------------------------------------------------------------
extern "C" void kernel_launch(void* const* d_in, const int* in_sizes, int n_in,
                              void* d_out, int out_size, void* d_ws, size_t ws_size,
                              hipStream_t stream) {
    const float* qs    = (const float*)d_in[0];  // query_single [32,128]
    const float* ps    = (const float*)d_in[1];  // pos_single   [32,128]
    const float* qm3   = (const float*)d_in[2];  // query_multi  [32,256,128]
    const float* pm3   = (const float*)d_in[3];  // pos_multi    [32,256,128]
    const void*  qmask = d_in[4];                // q_mask [32,256]
    const void*  pmask = d_in[5];                // p_mask [32,256]
    float* out = (float*)d_out;

    const int NTOK = B_SZ * T_SZ * D_SZ;         // 1,048,576
    unsigned short* Qbf = (unsigned short*)d_ws;
    unsigned short* Pbf = Qbf + NTOK;
    float* sraw = (float*)(Pbf + NTOK);          // [1024]

    hipMemsetAsync(out, 0, 4 * sizeof(float), stream);  // atomics accumulate
    cvt2<<<512, 256, 0, stream>>>(qm3, pm3, Qbf, Pbf);
    late3<<<512, 512, 0, stream>>>(Qbf, Pbf, qmask, pmask, sraw);
    loss_row2<<<B_SZ, 256, 0, stream>>>(qs, ps, sraw, qmask, out);
}

// Round 18
// 34.317 us; speedup vs baseline: 3.3935x; 1.0526x over previous
//
#include <hip/hip_runtime.h>
#include <hip/hip_bf16.h>

// Problem constants (from reference): B=32, T=256, D=128, tau=0.02
#define B_SZ 32
#define T_SZ 256
#define D_SZ 128
#define TAU_INV 50.0f

typedef __bf16 bf16x8 __attribute__((ext_vector_type(8)));
typedef float f32x4 __attribute__((ext_vector_type(4)));

__device__ __forceinline__ unsigned short f2bf(float f) {
    union { float f; unsigned int u; } v; v.f = f;
    unsigned int r = v.u + 0x7fffu + ((v.u >> 16) & 1u);  // RNE
    return (unsigned short)(r >> 16);
}

// masks arrive either as int32 (harness "integer -> int*") or raw bool bytes.
// Element [0][0] is always true (q_len,p_len >= 64), so int32 layout reads 1,
// byte layout reads 0x01010101. Deterministic (input-only) detection.
__device__ __forceinline__ bool mask_is_byte(const void* m) {
    return ((const int*)m)[0] != 1;
}
__device__ __forceinline__ int mget(const void* m, int idx, bool isb) {
    return isb ? (((const unsigned char*)m)[idx] != 0) : (((const int*)m)[idx] != 0);
}

// ---------------- Kernel A: fp32->bf16 + mask tables ------------------------
// Blocks 0..511: convert (each thread 8 elems of Q AND 8 of P).
// Blocks 512..543: one block per batch row r -> maddF/qmulF, p_hi[r], tcnt[r].
__global__ __launch_bounds__(256) void cvt_prep2(
    const float* __restrict__ qsrc, const float* __restrict__ psrc,
    const void* __restrict__ qmask, const void* __restrict__ pmask,
    unsigned short* __restrict__ Qb, unsigned short* __restrict__ Pb,
    float* __restrict__ maddF, float* __restrict__ qmulF,
    int* __restrict__ p_hiA, float* __restrict__ tcntA) {
    const int tid = threadIdx.x;
    if (blockIdx.x < 512) {
        int i = (blockIdx.x * 256 + tid) * 8;
        const float4* q4 = (const float4*)(qsrc + i);
        const float4* p4 = (const float4*)(psrc + i);
        float4 a0 = q4[0], a1 = q4[1], b0 = p4[0], b1 = p4[1];
        ushort4 oq0 = { f2bf(a0.x), f2bf(a0.y), f2bf(a0.z), f2bf(a0.w) };
        ushort4 oq1 = { f2bf(a1.x), f2bf(a1.y), f2bf(a1.z), f2bf(a1.w) };
        ushort4 op0 = { f2bf(b0.x), f2bf(b0.y), f2bf(b0.z), f2bf(b0.w) };
        ushort4 op1 = { f2bf(b1.x), f2bf(b1.y), f2bf(b1.z), f2bf(b1.w) };
        *(ushort4*)(Qb + i)     = oq0;
        *(ushort4*)(Qb + i + 4) = oq1;
        *(ushort4*)(Pb + i)     = op0;
        *(ushort4*)(Pb + i + 4) = op1;
        return;
    }
    // ---- table row r: 1 thread per token, wave+LDS reduce ----
    __shared__ int sl[4], sc[4];
    const bool isb = mask_is_byte(qmask);
    const int r = blockIdx.x - 512;              // 0..31
    const int t = tid;                           // 0..255 (= T_SZ)
    const int pm = mget(pmask, r * T_SZ + t, isb);
    const int qm = mget(qmask, r * T_SZ + t, isb);
    maddF[r * T_SZ + t] = pm ? 0.0f : -1e30f;
    qmulF[r * T_SZ + t] = qm ? 1.0f : 0.0f;
    int lp = pm ? t + 1 : 0, cq = qm;
    #pragma unroll
    for (int off = 1; off < 64; off <<= 1) {
        int o = __shfl_xor(lp, off);
        lp = o > lp ? o : lp;
        cq += __shfl_xor(cq, off);
    }
    if ((tid & 63) == 0) { sl[tid >> 6] = lp; sc[tid >> 6] = cq; }
    __syncthreads();
    if (tid == 0) {
        int LP = sl[0], CQ = sc[0];
        #pragma unroll
        for (int i = 1; i < 4; ++i) { LP = sl[i] > LP ? sl[i] : LP; CQ += sc[i]; }
        p_hiA[r] = LP > 1 ? LP : 1;
        tcntA[r] = (float)(CQ > 1 ? CQ : 1);
    }
}

// ---------------- Kernel B: late-interaction, 2 c's per block ---------------
// 256 blocks x 1024 threads, 1 block/CU, 16 waves. Block (bg, cp): b0=bg,
// b1=bg+16, c0=2cp, c1=2cp+1. Waves 0-7 own b0 (32 q-rows each), 8-15 own b1.
// P tiles double-buffered in 128 KB LDS: stage c0 -> barrier -> issue c1
// stage -> compute c0 (c1 latency hidden) -> barrier -> compute c1.
// global_load_lds with linear LDS dest + inverse-swizzled global source;
// swizzled reads make it net-identity (rule #21).
__global__ __launch_bounds__(1024, 4) void late_sim2(
    const unsigned short* __restrict__ Qbf, const unsigned short* __restrict__ Pbf,
    const float* __restrict__ maddF, const float* __restrict__ qmulF,
    const int* __restrict__ p_hiA, float* __restrict__ sraw)
{
    __shared__ __align__(16) unsigned char Pl[2][T_SZ * D_SZ * 2]; // 2 x 64 KB
    __shared__ float maddL[2][T_SZ];
    __shared__ float qmulL[2][T_SZ];
    __shared__ float wsum[16][2];

    const int tid = threadIdx.x;
    const int l   = tid & 63;
    const int w   = tid >> 6;            // wave 0..15
    const int bid = blockIdx.x;
    const int xcd = bid & 7;
    const int j   = bid >> 3;            // 0..31
    const int bg  = xcd * 2 + (j >> 4);  // XCD-local bg
    const int cp  = j & 15;
    const int c0  = cp * 2, c1 = cp * 2 + 1;
    const int b0  = bg, b1 = bg + 16;
    const int lr  = l & 15;
    const int lg  = l >> 4;
    const int wb  = w >> 3;              // 0: b0 waves, 1: b1 waves
    const int myb = wb ? b1 : b0;
    const int s   = (w & 7) * 32;        // this wave's q-row strip

    const int p_hi0 = p_hiA[c0], p_hi1 = p_hiA[c1];
    const int pt0 = (p_hi0 + 15) >> 4, st0 = (p_hi0 + 63) >> 6;
    const int pt1 = (p_hi1 + 15) >> 4, st1 = (p_hi1 + 63) >> 6;

    // wave-uniform q activity for this wave's 32 rows
    const bool dob = __any(qmulF[myb * T_SZ + s + (l & 31)] > 0.0f);

    // Q fragments (one b per wave): lane holds Q[s+qt*16+lr][k*32+lg*8 .. +7]
    bf16x8 qf[2][4] = {};
    if (dob)
        #pragma unroll
        for (int qt = 0; qt < 2; ++qt)
            #pragma unroll
            for (int k = 0; k < 4; ++k)
                qf[qt][k] = *(const bf16x8*)(Qbf + myb * (T_SZ * D_SZ)
                              + (s + qt * 16 + lr) * D_SZ + k * 32 + lg * 8);

    // stage c0 (buffer 0): 1024 thr x 16B = 64 rows per iteration
    {
        const unsigned short* Pc = Pbf + c0 * (T_SZ * D_SZ);
        for (int it = 0; it < st0; ++it) {
            int m   = it * 1024 + tid;           // linear 16B chunk id
            int row = m >> 4;
            int cj  = m & 15;
            const unsigned short* src = Pc + row * D_SZ + ((cj ^ (row & 7)) << 3);
            __builtin_amdgcn_global_load_lds(
                (const __attribute__((address_space(1))) unsigned int*)src,
                (__attribute__((address_space(3))) unsigned int*)(Pl[0] + (it * 1024 + w * 64) * 16),
                16, 0, 0);
        }
    }
    // mask vectors (from precomputed tables)
    if (tid < 64) {
        *(float4*)(maddL[0] + tid * 4) = *(const float4*)(maddF + c0 * T_SZ + tid * 4);
    } else if (tid < 128) {
        int t = tid - 64;
        *(float4*)(maddL[1] + t * 4) = *(const float4*)(maddF + c1 * T_SZ + t * 4);
    } else if (tid < 192) {
        int t = tid - 128;
        *(float4*)(qmulL[0] + t * 4) = *(const float4*)(qmulF + b0 * T_SZ + t * 4);
    } else if (tid < 256) {
        int t = tid - 192;
        *(float4*)(qmulL[1] + t * 4) = *(const float4*)(qmulF + b1 * T_SZ + t * 4);
    }
    __syncthreads();                             // c0 + masks ready

    // issue c1 staging (buffer 1) — hides under c0 compute
    {
        const unsigned short* Pc = Pbf + c1 * (T_SZ * D_SZ);
        for (int it = 0; it < st1; ++it) {
            int m   = it * 1024 + tid;
            int row = m >> 4;
            int cj  = m & 15;
            const unsigned short* src = Pc + row * D_SZ + ((cj ^ (row & 7)) << 3);
            __builtin_amdgcn_global_load_lds(
                (const __attribute__((address_space(1))) unsigned int*)src,
                (__attribute__((address_space(3))) unsigned int*)(Pl[1] + (it * 1024 + w * 64) * 16),
                16, 0, 0);
        }
    }

    float r00 = -3e38f, r01 = -3e38f;            // c0: qt0, qt1
    float r10 = -3e38f, r11 = -3e38f;            // c1: qt0, qt1

    for (int pt = 0; pt < pt0; ++pt) {           // ---- compute c0 ----
        f32x4 a0 = {0,0,0,0}, a1 = {0,0,0,0};
        #pragma unroll
        for (int k = 0; k < 4; ++k) {
            int row = pt * 16 + lr;
            bf16x8 af = *(const bf16x8*)(Pl[0] + row * 256 + (((k * 4 + lg) ^ (row & 7)) << 4));
            if (dob) {
                a0 = __builtin_amdgcn_mfma_f32_16x16x32_bf16(af, qf[0][k], a0, 0, 0, 0);
                a1 = __builtin_amdgcn_mfma_f32_16x16x32_bf16(af, qf[1][k], a1, 0, 0, 0);
            }
        }
        float pm0 = maddL[0][pt * 16 + lg * 4 + 0];
        float pm1 = maddL[0][pt * 16 + lg * 4 + 1];
        float pm2 = maddL[0][pt * 16 + lg * 4 + 2];
        float pm3 = maddL[0][pt * 16 + lg * 4 + 3];
        if (dob) {
            r00 = fmaxf(r00, fmaxf(fmaxf(a0[0]+pm0, a0[1]+pm1), fmaxf(a0[2]+pm2, a0[3]+pm3)));
            r01 = fmaxf(r01, fmaxf(fmaxf(a1[0]+pm0, a1[1]+pm1), fmaxf(a1[2]+pm2, a1[3]+pm3)));
        }
    }
    __syncthreads();                             // c1 staged (vmcnt drained)

    for (int pt = 0; pt < pt1; ++pt) {           // ---- compute c1 ----
        f32x4 a0 = {0,0,0,0}, a1 = {0,0,0,0};
        #pragma unroll
        for (int k = 0; k < 4; ++k) {
            int row = pt * 16 + lr;
            bf16x8 af = *(const bf16x8*)(Pl[1] + row * 256 + (((k * 4 + lg) ^ (row & 7)) << 4));
            if (dob) {
                a0 = __builtin_amdgcn_mfma_f32_16x16x32_bf16(af, qf[0][k], a0, 0, 0, 0);
                a1 = __builtin_amdgcn_mfma_f32_16x16x32_bf16(af, qf[1][k], a1, 0, 0, 0);
            }
        }
        float pm0 = maddL[1][pt * 16 + lg * 4 + 0];
        float pm1 = maddL[1][pt * 16 + lg * 4 + 1];
        float pm2 = maddL[1][pt * 16 + lg * 4 + 2];
        float pm3 = maddL[1][pt * 16 + lg * 4 + 3];
        if (dob) {
            r10 = fmaxf(r10, fmaxf(fmaxf(a0[0]+pm0, a0[1]+pm1), fmaxf(a0[2]+pm2, a0[3]+pm3)));
            r11 = fmaxf(r11, fmaxf(fmaxf(a1[0]+pm0, a1[1]+pm1), fmaxf(a1[2]+pm2, a1[3]+pm3)));
        }
    }

    // combine the 4 row-groups (lanes x, 16+x, 32+x, 48+x)
    r00 = fmaxf(r00, __shfl_xor(r00, 16)); r00 = fmaxf(r00, __shfl_xor(r00, 32));
    r01 = fmaxf(r01, __shfl_xor(r01, 16)); r01 = fmaxf(r01, __shfl_xor(r01, 32));
    r10 = fmaxf(r10, __shfl_xor(r10, 16)); r10 = fmaxf(r10, __shfl_xor(r10, 32));
    r11 = fmaxf(r11, __shfl_xor(r11, 16)); r11 = fmaxf(r11, __shfl_xor(r11, 32));

    // masked sum over this wave's 32 q tokens (each value replicated 4x)
    float t0 = r00 * qmulL[wb][s + lr] + r01 * qmulL[wb][s + 16 + lr];   // c0
    float t1 = r10 * qmulL[wb][s + lr] + r11 * qmulL[wb][s + 16 + lr];   // c1
    #pragma unroll
    for (int off = 32; off > 0; off >>= 1) {
        t0 += __shfl_down(t0, off);
        t1 += __shfl_down(t1, off);
    }
    if (l == 0) { wsum[w][0] = t0 * 0.25f; wsum[w][1] = t1 * 0.25f; }
    __syncthreads();

    if (tid < 4) {                               // tid: bit0=c, bit1=b
        const int bsel = tid >> 1, csel = tid & 1;
        float sum = 0.f;
        #pragma unroll
        for (int ww = 0; ww < 8; ++ww) sum += wsum[bsel * 8 + ww][csel];
        sraw[(bsel ? b1 : b0) * 32 + (csel ? c1 : c0)] = sum;
    }
}

// ---------------- Kernel C: losses, one block PER ROW (32 blocks) -----------
__global__ __launch_bounds__(256) void loss_row(
    const float* __restrict__ qs, const float* __restrict__ ps,
    const float* __restrict__ sraw, const float* __restrict__ tcntA,
    float* __restrict__ out)
{
    __shared__ float denseL[B_SZ], lateL[B_SZ];
    const int r   = blockIdx.x;
    const int tid = threadIdx.x;
    const int cc  = tid >> 3;        // column 0..31
    const int j   = tid & 7;         // 16-elem chunk within the dot

    // dot(qs[r], ps[cc]): 8 threads x 16 elems (4x float4), 3-round reduce
    {
        const float4* qa = (const float4*)(qs + r  * D_SZ + j * 16);
        const float4* pb = (const float4*)(ps + cc * D_SZ + j * 16);
        float s = 0.f;
        #pragma unroll
        for (int v = 0; v < 4; ++v) {
            float4 q = qa[v], p = pb[v];
            s += q.x * p.x + q.y * p.y + q.z * p.z + q.w * p.w;
        }
        s += __shfl_xor(s, 1);
        s += __shfl_xor(s, 2);
        s += __shfl_xor(s, 4);
        if (j == 0) denseL[cc] = s;
    }
    if (tid < B_SZ) lateL[tid] = sraw[r * 32 + tid] / tcntA[r];
    __syncthreads();

    if (tid >= 32) return;
    const int lane = tid;
    float xd = denseL[lane] * TAU_INV;
    float xl = lateL[lane]  * TAU_INV;
    float md = xd, ml = xl;
    #pragma unroll
    for (int off = 16; off > 0; off >>= 1) {
        md = fmaxf(md, __shfl_xor(md, off));
        ml = fmaxf(ml, __shfl_xor(ml, off));
    }
    float sd = expf(xd - md), sl = expf(xl - ml);
    #pragma unroll
    for (int off = 16; off > 0; off >>= 1) {
        sd += __shfl_xor(sd, off);
        sl += __shfl_xor(sl, off);
    }
    float lsd = md + logf(sd);
    float lsl = ml + logf(sl);
    float pd = expf(xd - lsd);
    float pl = expf(xl - lsl);
    float klt = pd * logf((pd + 1e-8f) / (pl + 1e-8f));
    #pragma unroll
    for (int off = 16; off > 0; off >>= 1) klt += __shfl_xor(klt, off);

    float logpd = xd - lsd;
    float logpl = xl - lsl;
    float dlogd = __shfl(logpd, r);
    float dlogl = __shfl(logpl, r);

    if (lane == 0) {
        const float inv = 1.0f / (float)B_SZ;
        float a = -dlogd * inv;
        float b = -dlogl * inv;
        float k = klt * inv;
        atomicAdd(out + 1, a);
        atomicAdd(out + 2, b);
        atomicAdd(out + 3, k);
        atomicAdd(out + 0, a + b + k);
    }
}

// ---------------------------------------------------------------------------
extern "C" void kernel_launch(void* const* d_in, const int* in_sizes, int n_in,
                              void* d_out, int out_size, void* d_ws, size_t ws_size,
                              hipStream_t stream) {
    const float* qs    = (const float*)d_in[0];  // query_single [32,128]
    const float* ps    = (const float*)d_in[1];  // pos_single   [32,128]
    const float* qm3   = (const float*)d_in[2];  // query_multi  [32,256,128]
    const float* pm3   = (const float*)d_in[3];  // pos_multi    [32,256,128]
    const void*  qmask = d_in[4];                // q_mask [32,256]
    const void*  pmask = d_in[5];                // p_mask [32,256]
    float* out = (float*)d_out;

    const int NTOK = B_SZ * T_SZ * D_SZ;         // 1,048,576
    unsigned short* Qbf = (unsigned short*)d_ws;
    unsigned short* Pbf = Qbf + NTOK;
    float* sraw  = (float*)(Pbf + NTOK);         // [1024]
    float* maddF = sraw + 1024;                  // [32*256]
    float* qmulF = maddF + B_SZ * T_SZ;          // [32*256]
    int*   p_hiA = (int*)(qmulF + B_SZ * T_SZ);  // [32]
    float* tcntA = (float*)(p_hiA + 32);         // [32]

    hipMemsetAsync(out, 0, 4 * sizeof(float), stream);  // atomics accumulate
    cvt_prep2<<<544, 256, 0, stream>>>(qm3, pm3, qmask, pmask, Qbf, Pbf,
                                       maddF, qmulF, p_hiA, tcntA);
    late_sim2<<<256, 1024, 0, stream>>>(Qbf, Pbf, maddF, qmulF, p_hiA, sraw);
    loss_row<<<B_SZ, 256, 0, stream>>>(qs, ps, sraw, tcntA, out);
}